// Round 2
// baseline (15533.554 us; speedup 1.0000x reference)
//
#include <hip/hip_runtime.h>
#include <hip/hip_cooperative_groups.h>

namespace cg = cooperative_groups;

#define BATCHES 16
#define NG 2048
#define FDIM 1024
#define EPG 65536
#define NTOT (BATCHES*NG)      // 32768
#define ETOT (BATCHES*EPG)     // 1048576
#define STEPS 64
#define NBLK 512
#define NTHR 256
#define BLK_PER_BATCH (NBLK/BATCHES)          // 32
#define ROWS_PER_BLK (NG/BLK_PER_BATCH)       // 64
#define EDGE_PER_BLK (ETOT/NBLK)              // 2048

__device__ __forceinline__ double block_reduce_sum(double v, double* s_red) {
    for (int off = 32; off > 0; off >>= 1)
        v += __shfl_down(v, off, 64);
    __syncthreads();                 // protect s_red reuse across calls
    int lane = threadIdx.x & 63;
    int wave = threadIdx.x >> 6;
    if (lane == 0) s_red[wave] = v;
    __syncthreads();
    return (s_red[0] + s_red[1]) + (s_red[2] + s_red[3]);
}

__global__ __launch_bounds__(NTHR, 2)
void GradSolver_58102317580919_kernel(
    const float* __restrict__ x_start,
    const float* __restrict__ rhs,
    const float* __restrict__ proj,
    const float* __restrict__ q,
    const float* __restrict__ obj_solution,
    const int*   __restrict__ edge_index,   // [2, ETOT] int32
    const float* __restrict__ edge_weight,
    float* __restrict__ out,                // [NTOT bestx][B best][B*STEPS gaps]
    void* __restrict__ wsv)
{
    cg::grid_group grid = cg::this_grid();

    double* xb0  = (double*)wsv;         // N
    double* xb1  = xb0 + NTOT;           // N
    double* pred = xb1 + NTOT;           // N
    double* coef = pred + NTOT;          // B*F
    double* quad = coef + BATCHES*FDIM;  // B
    double* lin  = quad + BATCHES;       // B
    unsigned long long* minr = (unsigned long long*)(lin + BATCHES); // B

    const int tid   = threadIdx.x;
    const int bid   = blockIdx.x;
    const int batch = bid / BLK_PER_BATCH;
    const int n0    = (bid % BLK_PER_BATCH) * ROWS_PER_BLK;
    const int row_base = batch * NG + n0;

    const unsigned long long DINF = 0x7FF0000000000000ULL;

    __shared__ double s_d[ROWS_PER_BLK];
    __shared__ double s_coef[FDIM];
    __shared__ double s_red[4];
    __shared__ double s_bestobj;

    // ---------------- P0: init ----------------
    if (tid < ROWS_PER_BLK) {
        int gr = row_base + tid;
        xb0[gr] = (double)x_start[gr];
    }
    {   // zero coef: 16384 doubles / 512 blocks = 32 each
        const int per = (BATCHES*FDIM)/NBLK;
        if (tid < per) coef[bid*per + tid] = 0.0;
    }
    if (bid == 0 && tid < BATCHES) { quad[tid] = 0.0; lin[tid] = 0.0; minr[tid] = DINF; }
    if (tid == 0) s_bestobj = __longlong_as_double((long long)DINF); // +inf
    double tau = 1.0;
    grid.sync();

    // ---------------- P1: obj(x_start) ----------------
    {
        double lp = 0.0;
        if (tid < ROWS_PER_BLK) {
            int gr = row_base + tid;
            lp = (double)q[gr] * xb0[gr];
        }
        double ls = block_reduce_sum(lp, s_red);
        if (tid == 0) atomicAdd(&lin[batch], ls);

        const int e0 = bid * EDGE_PER_BLK;
        double qp = 0.0;
        #pragma unroll 4
        for (int j = 0; j < EDGE_PER_BLK/NTHR; ++j) {
            int e  = e0 + tid + j*NTHR;
            int si = edge_index[e];
            int di = edge_index[ETOT + e];
            qp += (double)edge_weight[e] * xb0[si] * xb0[di];
        }
        double qs = block_reduce_sum(qp, s_red);
        if (tid == 0) atomicAdd(&quad[batch], qs);
    }
    grid.sync();

    // ---------------- main loop ----------------
    for (int k = 0; k <= STEPS; ++k) {
        // ---- Phase A: finalize prev obj, direction, coef ----
        double cur = 0.5 * quad[batch] + lin[batch];
        double bo  = s_bestobj;
        bool better = cur < bo;
        double nb  = better ? cur : bo;
        __syncthreads();                 // everyone read s_bestobj
        if (tid == 0) s_bestobj = nb;

        if (k > 0 && (bid % BLK_PER_BATCH) == 0 && tid == 0) {
            double opt = (double)obj_solution[batch];
            out[NTOT + BATCHES + batch*STEPS + (k-1)] = (float)fabs((opt - nb)/opt);
        }

        double* xc = (k & 1) ? xb1 : xb0;
        double* xn = (k & 1) ? xb0 : xb1;

        if (better && tid < ROWS_PER_BLK) {
            int gr = row_base + tid;
            out[gr] = (float)xc[gr];     // best_x
        }
        if (k == STEPS) {
            if ((bid % BLK_PER_BATCH) == 0 && tid == 0) {
                double opt = (double)obj_solution[batch];
                out[NTOT + batch] = (float)fabs((opt - nb)/opt);   // best
            }
            break;
        }

        if (bid == 0 && tid < BATCHES) minr[tid] = DINF;  // reset for B

        if (tid < ROWS_PER_BLK) {
            int gr = row_base + tid;
            double xv = xc[gr];
            s_d[tid] = -xv + (double)rhs[gr] + 0.1 * tau / (xv + tau);
        }
        tau = fmax(tau * 0.5, 1e-5);
        __syncthreads();

        {   // coef accumulation: thread t owns f = 4t..4t+3
            double a0 = 0.0, a1 = 0.0, a2 = 0.0, a3 = 0.0;
            const float4* P4 = (const float4*)(proj + (size_t)row_base * FDIM);
            #pragma unroll 8
            for (int r = 0; r < ROWS_PER_BLK; ++r) {
                float4 p = P4[r*(FDIM/4) + tid];
                double dv = s_d[r];
                a0 += (double)p.x*dv; a1 += (double)p.y*dv;
                a2 += (double)p.z*dv; a3 += (double)p.w*dv;
            }
            double* cf = coef + batch*FDIM + 4*tid;
            atomicAdd(cf+0, a0); atomicAdd(cf+1, a1);
            atomicAdd(cf+2, a2); atomicAdd(cf+3, a3);
        }
        grid.sync();

        // ---- Phase B: pred rows + min ratio ----
        if (bid == 0 && tid < BATCHES) { quad[tid] = 0.0; lin[tid] = 0.0; }
        {
            const double2* g2 = (const double2*)(coef + batch*FDIM);
            ((double2*)s_coef)[tid]       = g2[tid];
            ((double2*)s_coef)[tid + 256] = g2[tid + 256];
        }
        __syncthreads();

        {
            const int wave = tid >> 6, lane = tid & 63;
            // hoist this lane's coef slice (features 4*(lane+64j)..+3, j=0..3)
            double c[16];
            #pragma unroll
            for (int j = 0; j < 4; ++j) {
                int f = 4*(lane + 64*j);
                c[4*j+0] = s_coef[f+0]; c[4*j+1] = s_coef[f+1];
                c[4*j+2] = s_coef[f+2]; c[4*j+3] = s_coef[f+3];
            }
            double wmin = 1e300;
            for (int i = 0; i < ROWS_PER_BLK/4; ++i) {   // 16 rows per wave
                int r  = wave * (ROWS_PER_BLK/4) + i;
                int gr = row_base + r;
                const float4* Pr = (const float4*)(proj + (size_t)gr * FDIM);
                double dot = 0.0;
                #pragma unroll
                for (int j = 0; j < 4; ++j) {
                    float4 p = Pr[lane + 64*j];
                    dot += (double)p.x*c[4*j+0] + (double)p.y*c[4*j+1]
                         + (double)p.z*c[4*j+2] + (double)p.w*c[4*j+3];
                }
                for (int off = 32; off > 0; off >>= 1)
                    dot += __shfl_down(dot, off, 64);
                if (lane == 0) {
                    pred[gr] = dot;
                    if (dot < 0.0) wmin = fmin(wmin, xc[gr] / (-dot));
                }
            }
            if (lane == 0)
                atomicMin(&minr[batch], (unsigned long long)__double_as_longlong(wmin));
        }
        grid.sync();

        // ---- Phase C: x update + lin + edge quad ----
        {   // zero coef for next iter
            const int per = (BATCHES*FDIM)/NBLK;
            if (tid < per) coef[bid*per + tid] = 0.0;
        }
        double alpha = fmin(__longlong_as_double((long long)minr[batch]), 1.0) * 0.995;

        double lp = 0.0;
        if (tid < ROWS_PER_BLK) {
            int gr = row_base + tid;
            double xv = xc[gr] + alpha * pred[gr];
            xn[gr] = xv;
            lp = (double)q[gr] * xv;
        }
        double ls = block_reduce_sum(lp, s_red);
        if (tid == 0) atomicAdd(&lin[batch], ls);

        {
            const int e0 = bid * EDGE_PER_BLK;
            double qp = 0.0;
            #pragma unroll 4
            for (int j = 0; j < EDGE_PER_BLK/NTHR; ++j) {
                int e  = e0 + tid + j*NTHR;
                int si = edge_index[e];
                int di = edge_index[ETOT + e];
                double xs = xc[si] + alpha * pred[si];
                double xd = xc[di] + alpha * pred[di];
                qp += (double)edge_weight[e] * xs * xd;
            }
            double qs = block_reduce_sum(qp, s_red);
            if (tid == 0) atomicAdd(&quad[batch], qs);
        }
        grid.sync();
    }
}

extern "C" void kernel_launch(void* const* d_in, const int* in_sizes, int n_in,
                              void* d_out, int out_size, void* d_ws, size_t ws_size,
                              hipStream_t stream) {
    const float* x_start      = (const float*)d_in[0];
    const float* rhs          = (const float*)d_in[1];
    const float* proj         = (const float*)d_in[2];
    const float* q            = (const float*)d_in[3];
    const float* obj_solution = (const float*)d_in[4];
    const int*   edge_index   = (const int*)d_in[5];
    const float* edge_weight  = (const float*)d_in[6];
    // d_in[7] = vals_batch (derivable: batch = index / 2048) — unused
    float* out = (float*)d_out;
    void* ws   = d_ws;

    void* args[] = { (void*)&x_start, (void*)&rhs, (void*)&proj, (void*)&q,
                     (void*)&obj_solution, (void*)&edge_index, (void*)&edge_weight,
                     (void*)&out, (void*)&ws };
    hipLaunchCooperativeKernel((void*)GradSolver_58102317580919_kernel,
                               dim3(NBLK), dim3(NTHR), args, 0, stream);
}